// Round 6
// baseline (75.727 us; speedup 1.0000x reference)
//
#include <hip/hip_runtime.h>
#include <math.h>

#define N0 2048
#define N1 1024
#define T0 128                    // layer-0 tile edge
#define T1 64                     // layer-1 tile edge
#define M0 (N0 / T0)              // 16
#define M1 (N1 / T1)              // 16
#define NB0 (M0 * (M0 + 1) / 2)   // 136 lower-tri blocks, layer 0
#define NB1 (M1 * (M1 + 1) / 2)   // 136 lower-tri blocks, layer 1
#define NBTOT (NB0 + NB1)         // 272

// ws layout (float offsets): kn0[N0*9] inv0[N0*9] kn1[N1*25] inv1[N1*25]

// All-fp32 prep: normalize + invert + one Newton polish. Block=64 spreads the
// 3072 independent tasks over 48 CUs (serial chains overlap across lanes).
__global__ __launch_bounds__(64) void prep_kernel(const float* __restrict__ k0,
                                                  const float* __restrict__ k1,
                                                  float* __restrict__ kn0,
                                                  float* __restrict__ inv0,
                                                  float* __restrict__ kn1,
                                                  float* __restrict__ inv1) {
    int t = blockIdx.x * blockDim.x + threadIdx.x;
    if (t < N0) {
        float a[9];
        float ss = 0.0f;
#pragma unroll
        for (int e = 0; e < 9; ++e) { a[e] = k0[t * 9 + e]; ss = fmaf(a[e], a[e], ss); }
        float rn = 1.0f / (sqrtf(ss) + 1e-8f);
#pragma unroll
        for (int e = 0; e < 9; ++e) a[e] *= rn;
        float c00 = a[4] * a[8] - a[5] * a[7];
        float c01 = -(a[3] * a[8] - a[5] * a[6]);
        float c02 = a[3] * a[7] - a[4] * a[6];
        float det = a[0] * c00 + a[1] * c01 + a[2] * c02;
        float id = 1.0f / det;
        float x[9];
        x[0] = c00 * id;
        x[1] = (a[2] * a[7] - a[1] * a[8]) * id;
        x[2] = (a[1] * a[5] - a[2] * a[4]) * id;
        x[3] = c01 * id;
        x[4] = (a[0] * a[8] - a[2] * a[6]) * id;
        x[5] = (a[2] * a[3] - a[0] * a[5]) * id;
        x[6] = c02 * id;
        x[7] = (a[1] * a[6] - a[0] * a[7]) * id;
        x[8] = (a[0] * a[4] - a[1] * a[3]) * id;
        // Newton: x <- x(2I - a x)
        float r[9];
#pragma unroll
        for (int i = 0; i < 3; ++i)
#pragma unroll
            for (int j = 0; j < 3; ++j) {
                float m = a[i * 3 + 0] * x[j];
                m = fmaf(a[i * 3 + 1], x[3 + j], m);
                m = fmaf(a[i * 3 + 2], x[6 + j], m);
                r[i * 3 + j] = ((i == j) ? 2.0f : 0.0f) - m;
            }
#pragma unroll
        for (int i = 0; i < 3; ++i)
#pragma unroll
            for (int j = 0; j < 3; ++j) {
                float m = x[i * 3 + 0] * r[j];
                m = fmaf(x[i * 3 + 1], r[3 + j], m);
                m = fmaf(x[i * 3 + 2], r[6 + j], m);
                inv0[t * 9 + i * 3 + j] = m;
            }
#pragma unroll
        for (int e = 0; e < 9; ++e) kn0[t * 9 + e] = a[e];
    } else {
        int u = t - N0;
        if (u < N1) {
            float A[5][5], B[5][5], K[5][5];
            float ss = 0.0f;
#pragma unroll
            for (int r = 0; r < 5; ++r)
#pragma unroll
                for (int c = 0; c < 5; ++c) {
                    float v = k1[u * 25 + r * 5 + c];
                    A[r][c] = v;
                    ss = fmaf(v, v, ss);
                }
            float rn = 1.0f / (sqrtf(ss) + 1e-8f);
#pragma unroll
            for (int r = 0; r < 5; ++r)
#pragma unroll
                for (int c = 0; c < 5; ++c) {
                    A[r][c] *= rn;
                    K[r][c] = A[r][c];
                    kn1[u * 25 + r * 5 + c] = A[r][c];
                    B[r][c] = (r == c) ? 1.0f : 0.0f;
                }
#pragma unroll
            for (int k = 0; k < 5; ++k) {
                // branchless bubble-max partial pivot (static indices only)
#pragma unroll
                for (int r = k + 1; r < 5; ++r) {
                    bool sw = fabsf(A[r][k]) > fabsf(A[k][k]);
#pragma unroll
                    for (int c = k; c < 5; ++c) {
                        float Ar = A[r][c], Ak = A[k][c];
                        A[r][c] = sw ? Ak : Ar;
                        A[k][c] = sw ? Ar : Ak;
                    }
#pragma unroll
                    for (int c = 0; c < 5; ++c) {
                        float Br = B[r][c], Bk = B[k][c];
                        B[r][c] = sw ? Bk : Br;
                        B[k][c] = sw ? Br : Bk;
                    }
                }
                float piv = 1.0f / A[k][k];
#pragma unroll
                for (int c = k; c < 5; ++c) A[k][c] *= piv;
#pragma unroll
                for (int c = 0; c < 5; ++c) B[k][c] *= piv;
#pragma unroll
                for (int r = 0; r < 5; ++r) {
                    if (r == k) continue;
                    float f = A[r][k];
#pragma unroll
                    for (int c = k; c < 5; ++c) A[r][c] = fmaf(-f, A[k][c], A[r][c]);
#pragma unroll
                    for (int c = 0; c < 5; ++c) B[r][c] = fmaf(-f, B[k][c], B[r][c]);
                }
            }
            // Newton: B <- B(2I - K B)
            float R[5][5];
#pragma unroll
            for (int i = 0; i < 5; ++i)
#pragma unroll
                for (int j = 0; j < 5; ++j) {
                    float m = K[i][0] * B[0][j];
#pragma unroll
                    for (int k = 1; k < 5; ++k) m = fmaf(K[i][k], B[k][j], m);
                    R[i][j] = ((i == j) ? 2.0f : 0.0f) - m;
                }
#pragma unroll
            for (int i = 0; i < 5; ++i)
#pragma unroll
                for (int j = 0; j < 5; ++j) {
                    float m = B[i][0] * R[0][j];
#pragma unroll
                    for (int k = 1; k < 5; ++k) m = fmaf(B[i][k], R[k][j], m);
                    inv1[u * 25 + i * 5 + j] = m;
                }
        }
    }
}

__device__ __forceinline__ void tri_decode(int t, int& bi, int& bj) {
    bi = (int)((sqrtf(8.0f * t + 1.0f) - 1.0f) * 0.5f);
    while ((bi + 1) * (bi + 2) / 2 <= t) ++bi;
    while (bi * (bi + 1) / 2 > t) --bi;
    bj = t - bi * (bi + 1) / 2;
}

// Pairs kernel, triangular grid. Lane->row mapping uses stride-16 interleave
// (i = ty + 16u, j = tx + 16v) so LDS lane stride is 9 (resp. 25) floats --
// coprime with 32 banks -> conflict-free. One pre-scaled float atomic per
// block into d_out (272 total; 0xAA poison of d_out = -3.03e-13, absorbed).
__global__ __launch_bounds__(256) void pairs_kernel(const float* __restrict__ inv0,
                                                    const float* __restrict__ kn0,
                                                    const float* __restrict__ inv1,
                                                    const float* __restrict__ kn1,
                                                    float* __restrict__ out) {
    __shared__ float sA[1600];  // L0: 128*9=1152; L1: 64*25=1600
    __shared__ float sB[1600];
    int tid = threadIdx.x;
    float contrib = 0.0f;
    bool isL0 = blockIdx.x < NB0;

    if (isL0) {
        // ---------------- layer 0: d=3, 128-tile, 8x8 pairs/thread ----------------
        int bi, bj;
        tri_decode(blockIdx.x, bi, bj);
        for (int e = tid; e < T0 * 9; e += 256) {
            sA[e] = inv0[bi * (T0 * 9) + e];
            sB[e] = kn0[bj * (T0 * 9) + e];
        }
        __syncthreads();

        int ty = tid >> 4, tx = tid & 15;
        float a[8][9];
#pragma unroll
        for (int u = 0; u < 8; ++u)
#pragma unroll
            for (int e = 0; e < 9; ++e) a[u][e] = sA[(ty + 16 * u) * 9 + e];
#pragma unroll
        for (int v = 0; v < 8; ++v) {
            float b[9];
#pragma unroll
            for (int e = 0; e < 9; ++e) b[e] = sB[(tx + 16 * v) * 9 + e];
            int j = bj * T0 + tx + 16 * v;
#pragma unroll
            for (int u = 0; u < 8; ++u) {
                float s = 0.0f;
#pragma unroll
                for (int r = 0; r < 3; ++r)
#pragma unroll
                    for (int c = 0; c < 3; ++c) {
                        float m = a[u][r * 3 + 0] * b[c];
                        m = fmaf(a[u][r * 3 + 1], b[3 + c], m);
                        m = fmaf(a[u][r * 3 + 2], b[6 + c], m);
                        float d = ((r == c) ? 1.0f : 0.0f) - m;
                        s = fmaf(d, d, s);
                    }
                int i = bi * T0 + ty + 16 * u;
                bool take = (i > j) && (s < 1.0f);
                contrib += take ? (1.0f - sqrtf(s)) : 0.0f;
            }
        }
    } else {
        // ---------------- layer 1: d=5, 64-tile, 4x4 pairs/thread ----------------
        int bi, bj;
        tri_decode(blockIdx.x - NB0, bi, bj);
        for (int e = tid; e < T1 * 25; e += 256) {
            sA[e] = inv1[bi * (T1 * 25) + e];
            sB[e] = kn1[bj * (T1 * 25) + e];
        }
        __syncthreads();

        int ty = tid >> 4, tx = tid & 15;
        float a[4][25];
#pragma unroll
        for (int u = 0; u < 4; ++u)
#pragma unroll
            for (int e = 0; e < 25; ++e) a[u][e] = sA[(ty + 16 * u) * 25 + e];
#pragma unroll
        for (int v = 0; v < 4; ++v) {
            float b[25];
#pragma unroll
            for (int e = 0; e < 25; ++e) b[e] = sB[(tx + 16 * v) * 25 + e];
            int j = bj * T1 + tx + 16 * v;
#pragma unroll
            for (int u = 0; u < 4; ++u) {
                float s = 0.0f;
#pragma unroll
                for (int r = 0; r < 5; ++r)
#pragma unroll
                    for (int c = 0; c < 5; ++c) {
                        float m = a[u][r * 5 + 0] * b[c];
#pragma unroll
                        for (int k = 1; k < 5; ++k) m = fmaf(a[u][r * 5 + k], b[k * 5 + c], m);
                        float d = ((r == c) ? 1.0f : 0.0f) - m;
                        s = fmaf(d, d, s);
                    }
                int i = bi * T1 + ty + 16 * u;
                bool take = (i > j) && (s < 1.0f);
                contrib += take ? (1.0f - sqrtf(s)) : 0.0f;
            }
        }
    }

    // block reduction -> one pre-scaled float atomic per block
#pragma unroll
    for (int off = 32; off; off >>= 1) contrib += __shfl_down(contrib, off);
    __shared__ float wsum[4];
    if ((tid & 63) == 0) wsum[tid >> 6] = contrib;
    __syncthreads();
    if (tid == 0) {
        double part = (double)(wsum[0] + wsum[1] + wsum[2] + wsum[3]);
        // final = S0/(n0(n0-1)) + S1/(n1(n1-1))  (2x lower-tri / 2-layer avg cancel)
        double scale = isL0 ? 1.0 / ((double)N0 * (double)(N0 - 1))
                            : 1.0 / ((double)N1 * (double)(N1 - 1));
        unsafeAtomicAdd(out, (float)(part * scale));  // native global_atomic_add_f32
    }
}

extern "C" void kernel_launch(void* const* d_in, const int* in_sizes, int n_in,
                              void* d_out, int out_size, void* d_ws, size_t ws_size,
                              hipStream_t stream) {
    const float* k0 = (const float*)d_in[0];   // (2048,3,3)
    const float* k1 = (const float*)d_in[1];   // (1024,5,5)
    float* out = (float*)d_out;

    float* ws = (float*)d_ws;
    float* kn0 = ws;
    float* inv0 = kn0 + N0 * 9;
    float* kn1 = inv0 + N0 * 9;
    float* inv1 = kn1 + N1 * 25;

    int totalPrep = N0 + N1;  // 3072 threads, block=64 -> 48 blocks
    prep_kernel<<<(totalPrep + 63) / 64, 64, 0, stream>>>(k0, k1, kn0, inv0, kn1, inv1);

    pairs_kernel<<<NBTOT, 256, 0, stream>>>(inv0, kn0, inv1, kn1, out);
}

// Round 7
// 70.119 us; speedup vs baseline: 1.0800x; 1.0800x over previous
//
#include <hip/hip_runtime.h>
#include <math.h>

#define N0 2048
#define N1 1024
#define T0 64                     // layer-0 tile edge
#define T1 32                     // layer-1 tile edge
#define M0 (N0 / T0)              // 32
#define M1 (N1 / T1)              // 32
#define NB0 (M0 * (M0 + 1) / 2)   // 528 lower-tri blocks, layer 0
#define NB1 (M1 * (M1 + 1) / 2)   // 528 lower-tri blocks, layer 1
#define NBTOT (NB0 + NB1)         // 1056

// ws layout (float offsets): kn0[N0*9] inv0[N0*9] kn1[N1*25] inv1[N1*25] partial[NBTOT]

// All-fp32 prep: normalize + invert + one Newton polish. Block=64 spreads the
// 3072 independent serial chains over 48 CUs.
__global__ __launch_bounds__(64) void prep_kernel(const float* __restrict__ k0,
                                                  const float* __restrict__ k1,
                                                  float* __restrict__ kn0,
                                                  float* __restrict__ inv0,
                                                  float* __restrict__ kn1,
                                                  float* __restrict__ inv1) {
    int t = blockIdx.x * blockDim.x + threadIdx.x;
    if (t < N0) {
        float a[9];
        float ss = 0.0f;
#pragma unroll
        for (int e = 0; e < 9; ++e) { a[e] = k0[t * 9 + e]; ss = fmaf(a[e], a[e], ss); }
        float rn = 1.0f / (sqrtf(ss) + 1e-8f);
#pragma unroll
        for (int e = 0; e < 9; ++e) a[e] *= rn;
        float c00 = a[4] * a[8] - a[5] * a[7];
        float c01 = -(a[3] * a[8] - a[5] * a[6]);
        float c02 = a[3] * a[7] - a[4] * a[6];
        float det = a[0] * c00 + a[1] * c01 + a[2] * c02;
        float id = 1.0f / det;
        float x[9];
        x[0] = c00 * id;
        x[1] = (a[2] * a[7] - a[1] * a[8]) * id;
        x[2] = (a[1] * a[5] - a[2] * a[4]) * id;
        x[3] = c01 * id;
        x[4] = (a[0] * a[8] - a[2] * a[6]) * id;
        x[5] = (a[2] * a[3] - a[0] * a[5]) * id;
        x[6] = c02 * id;
        x[7] = (a[1] * a[6] - a[0] * a[7]) * id;
        x[8] = (a[0] * a[4] - a[1] * a[3]) * id;
        // Newton: x <- x(2I - a x)
        float r[9];
#pragma unroll
        for (int i = 0; i < 3; ++i)
#pragma unroll
            for (int j = 0; j < 3; ++j) {
                float m = a[i * 3 + 0] * x[j];
                m = fmaf(a[i * 3 + 1], x[3 + j], m);
                m = fmaf(a[i * 3 + 2], x[6 + j], m);
                r[i * 3 + j] = ((i == j) ? 2.0f : 0.0f) - m;
            }
#pragma unroll
        for (int i = 0; i < 3; ++i)
#pragma unroll
            for (int j = 0; j < 3; ++j) {
                float m = x[i * 3 + 0] * r[j];
                m = fmaf(x[i * 3 + 1], r[3 + j], m);
                m = fmaf(x[i * 3 + 2], r[6 + j], m);
                inv0[t * 9 + i * 3 + j] = m;
            }
#pragma unroll
        for (int e = 0; e < 9; ++e) kn0[t * 9 + e] = a[e];
    } else {
        int u = t - N0;
        if (u < N1) {
            float A[5][5], B[5][5], K[5][5];
            float ss = 0.0f;
#pragma unroll
            for (int r = 0; r < 5; ++r)
#pragma unroll
                for (int c = 0; c < 5; ++c) {
                    float v = k1[u * 25 + r * 5 + c];
                    A[r][c] = v;
                    ss = fmaf(v, v, ss);
                }
            float rn = 1.0f / (sqrtf(ss) + 1e-8f);
#pragma unroll
            for (int r = 0; r < 5; ++r)
#pragma unroll
                for (int c = 0; c < 5; ++c) {
                    A[r][c] *= rn;
                    K[r][c] = A[r][c];
                    kn1[u * 25 + r * 5 + c] = A[r][c];
                    B[r][c] = (r == c) ? 1.0f : 0.0f;
                }
#pragma unroll
            for (int k = 0; k < 5; ++k) {
                // branchless bubble-max partial pivot (static indices only)
#pragma unroll
                for (int r = k + 1; r < 5; ++r) {
                    bool sw = fabsf(A[r][k]) > fabsf(A[k][k]);
#pragma unroll
                    for (int c = k; c < 5; ++c) {
                        float Ar = A[r][c], Ak = A[k][c];
                        A[r][c] = sw ? Ak : Ar;
                        A[k][c] = sw ? Ar : Ak;
                    }
#pragma unroll
                    for (int c = 0; c < 5; ++c) {
                        float Br = B[r][c], Bk = B[k][c];
                        B[r][c] = sw ? Bk : Br;
                        B[k][c] = sw ? Br : Bk;
                    }
                }
                float piv = 1.0f / A[k][k];
#pragma unroll
                for (int c = k; c < 5; ++c) A[k][c] *= piv;
#pragma unroll
                for (int c = 0; c < 5; ++c) B[k][c] *= piv;
#pragma unroll
                for (int r = 0; r < 5; ++r) {
                    if (r == k) continue;
                    float f = A[r][k];
#pragma unroll
                    for (int c = k; c < 5; ++c) A[r][c] = fmaf(-f, A[k][c], A[r][c]);
#pragma unroll
                    for (int c = 0; c < 5; ++c) B[r][c] = fmaf(-f, B[k][c], B[r][c]);
                }
            }
            // Newton: B <- B(2I - K B)
            float R[5][5];
#pragma unroll
            for (int i = 0; i < 5; ++i)
#pragma unroll
                for (int j = 0; j < 5; ++j) {
                    float m = K[i][0] * B[0][j];
#pragma unroll
                    for (int k = 1; k < 5; ++k) m = fmaf(K[i][k], B[k][j], m);
                    R[i][j] = ((i == j) ? 2.0f : 0.0f) - m;
                }
#pragma unroll
            for (int i = 0; i < 5; ++i)
#pragma unroll
                for (int j = 0; j < 5; ++j) {
                    float m = B[i][0] * R[0][j];
#pragma unroll
                    for (int k = 1; k < 5; ++k) m = fmaf(B[i][k], R[k][j], m);
                    inv1[u * 25 + i * 5 + j] = m;
                }
        }
    }
}

__device__ __forceinline__ void tri_decode(int t, int& bi, int& bj) {
    bi = (int)((sqrtf(8.0f * t + 1.0f) - 1.0f) * 0.5f);
    while ((bi + 1) * (bi + 2) / 2 <= t) ++bi;
    while (bi * (bi + 1) / 2 > t) --bi;
    bj = t - bi * (bi + 1) / 2;
}

// Pairs kernel, triangular grid, 1056 blocks (~4.1/CU for load balance).
// Row mapping i = ty + 16u / j = tx + 16v gives LDS lane strides of 9 (resp.
// 25) floats -- coprime with 32 banks -> conflict-free (<=2-way, which is free).
// Per-block partial written to ws (no same-address atomic serialization).
__global__ __launch_bounds__(256) void pairs_kernel(const float* __restrict__ inv0,
                                                    const float* __restrict__ kn0,
                                                    const float* __restrict__ inv1,
                                                    const float* __restrict__ kn1,
                                                    float* __restrict__ partial) {
    __shared__ float sA[800];  // L0: 64*9=576; L1: 32*25=800
    __shared__ float sB[800];
    int tid = threadIdx.x;
    float contrib = 0.0f;
    bool isL0 = blockIdx.x < NB0;

    if (isL0) {
        // ---------------- layer 0: d=3, 64-tile, 4x4 pairs/thread ----------------
        int bi, bj;
        tri_decode(blockIdx.x, bi, bj);
        for (int e = tid; e < T0 * 9; e += 256) {
            sA[e] = inv0[bi * (T0 * 9) + e];
            sB[e] = kn0[bj * (T0 * 9) + e];
        }
        __syncthreads();

        int ty = tid >> 4, tx = tid & 15;
        float a[4][9];
#pragma unroll
        for (int u = 0; u < 4; ++u)
#pragma unroll
            for (int e = 0; e < 9; ++e) a[u][e] = sA[(ty + 16 * u) * 9 + e];
#pragma unroll
        for (int v = 0; v < 4; ++v) {
            float b[9];
#pragma unroll
            for (int e = 0; e < 9; ++e) b[e] = sB[(tx + 16 * v) * 9 + e];
            int j = bj * T0 + tx + 16 * v;
#pragma unroll
            for (int u = 0; u < 4; ++u) {
                float s = 0.0f;
#pragma unroll
                for (int r = 0; r < 3; ++r)
#pragma unroll
                    for (int c = 0; c < 3; ++c) {
                        float m = a[u][r * 3 + 0] * b[c];
                        m = fmaf(a[u][r * 3 + 1], b[3 + c], m);
                        m = fmaf(a[u][r * 3 + 2], b[6 + c], m);
                        float d = ((r == c) ? 1.0f : 0.0f) - m;
                        s = fmaf(d, d, s);
                    }
                int i = bi * T0 + ty + 16 * u;
                bool take = (i > j) && (s < 1.0f);
                contrib += take ? (1.0f - sqrtf(s)) : 0.0f;
            }
        }
    } else {
        // ---------------- layer 1: d=5, 32-tile, 2x2 pairs/thread ----------------
        int bi, bj;
        tri_decode(blockIdx.x - NB0, bi, bj);
        for (int e = tid; e < T1 * 25; e += 256) {
            sA[e] = inv1[bi * (T1 * 25) + e];
            sB[e] = kn1[bj * (T1 * 25) + e];
        }
        __syncthreads();

        int ty = tid >> 4, tx = tid & 15;
        float a[2][25];
#pragma unroll
        for (int u = 0; u < 2; ++u)
#pragma unroll
            for (int e = 0; e < 25; ++e) a[u][e] = sA[(ty + 16 * u) * 25 + e];
#pragma unroll
        for (int v = 0; v < 2; ++v) {
            float b[25];
#pragma unroll
            for (int e = 0; e < 25; ++e) b[e] = sB[(tx + 16 * v) * 25 + e];
            int j = bj * T1 + tx + 16 * v;
#pragma unroll
            for (int u = 0; u < 2; ++u) {
                float s = 0.0f;
#pragma unroll
                for (int r = 0; r < 5; ++r)
#pragma unroll
                    for (int c = 0; c < 5; ++c) {
                        float m = a[u][r * 5 + 0] * b[c];
#pragma unroll
                        for (int k = 1; k < 5; ++k) m = fmaf(a[u][r * 5 + k], b[k * 5 + c], m);
                        float d = ((r == c) ? 1.0f : 0.0f) - m;
                        s = fmaf(d, d, s);
                    }
                int i = bi * T1 + ty + 16 * u;
                bool take = (i > j) && (s < 1.0f);
                contrib += take ? (1.0f - sqrtf(s)) : 0.0f;
            }
        }
    }

    // block reduction -> one partial per block
#pragma unroll
    for (int off = 32; off; off >>= 1) contrib += __shfl_down(contrib, off);
    __shared__ float wsum[4];
    if ((tid & 63) == 0) wsum[tid >> 6] = contrib;
    __syncthreads();
    if (tid == 0) partial[blockIdx.x] = wsum[0] + wsum[1] + wsum[2] + wsum[3];
}

__global__ void finalize_kernel(const float* __restrict__ partial, float* __restrict__ out) {
    int tid = threadIdx.x;
    double s0 = 0.0, s1 = 0.0;
    for (int x = tid; x < NB0; x += 256) s0 += (double)partial[x];
    for (int x = NB0 + tid; x < NBTOT; x += 256) s1 += (double)partial[x];
#pragma unroll
    for (int off = 32; off; off >>= 1) {
        s0 += __shfl_down(s0, off);
        s1 += __shfl_down(s1, off);
    }
    __shared__ double w0[4], w1[4];
    if ((tid & 63) == 0) { w0[tid >> 6] = s0; w1[tid >> 6] = s1; }
    __syncthreads();
    if (tid == 0) {
        double S0 = w0[0] + w0[1] + w0[2] + w0[3];
        double S1 = w1[0] + w1[1] + w1[2] + w1[3];
        // final = S0/(n0(n0-1)) + S1/(n1(n1-1))  (2x lower-tri / 2-layer avg cancel)
        double res = S0 / ((double)N0 * (double)(N0 - 1)) +
                     S1 / ((double)N1 * (double)(N1 - 1));
        out[0] = (float)res;
    }
}

extern "C" void kernel_launch(void* const* d_in, const int* in_sizes, int n_in,
                              void* d_out, int out_size, void* d_ws, size_t ws_size,
                              hipStream_t stream) {
    const float* k0 = (const float*)d_in[0];   // (2048,3,3)
    const float* k1 = (const float*)d_in[1];   // (1024,5,5)
    float* out = (float*)d_out;

    float* ws = (float*)d_ws;
    float* kn0 = ws;
    float* inv0 = kn0 + N0 * 9;
    float* kn1 = inv0 + N0 * 9;
    float* inv1 = kn1 + N1 * 25;
    float* partial = inv1 + N1 * 25;

    int totalPrep = N0 + N1;  // 3072 threads, block=64 -> 48 blocks
    prep_kernel<<<(totalPrep + 63) / 64, 64, 0, stream>>>(k0, k1, kn0, inv0, kn1, inv1);

    pairs_kernel<<<NBTOT, 256, 0, stream>>>(inv0, kn0, inv1, kn1, partial);

    finalize_kernel<<<1, 256, 0, stream>>>(partial, out);
}